// Round 4
// baseline (752.359 us; speedup 1.0000x reference)
//
#include <hip/hip_runtime.h>
#include <hip/hip_bf16.h>
#include <stdint.h>

#define D_IN 128
#define D_H 256
#define NLAYERS 5

typedef __bf16 bf16x8 __attribute__((ext_vector_type(8)));
typedef __bf16 bf16x4 __attribute__((ext_vector_type(4)));
typedef float f32x4 __attribute__((ext_vector_type(4)));
typedef unsigned short u16x8 __attribute__((ext_vector_type(8)));

// LDS mid-tile row stride in ushorts: 260 u16 = 520 B = 130 dwords (130%32=2
// -> rows spread across banks; measured SQ_LDS_BANK_CONFLICT==0 with this).
#define MID_STRIDE 260

__device__ inline __bf16 f2bf(float f) {
  __hip_bfloat16 h = __float2bfloat16(f);
  __bf16 r;
  __builtin_memcpy(&r, &h, sizeof(r));
  return r;
}

__device__ inline unsigned short bfbits(float f) {
  __hip_bfloat16 h = __float2bfloat16(f);
  unsigned short s;
  __builtin_memcpy(&s, &h, 2);
  return s;
}

__device__ inline float bf2f(unsigned short u) {
  return __uint_as_float((unsigned)u << 16);
}

// convert all 4 weight tensors to bf16 in one launch
__global__ void conv_weights(const float* __restrict__ a, const float* __restrict__ b,
                             const float* __restrict__ c, const float* __restrict__ d,
                             __hip_bfloat16* __restrict__ out) {
  int gid = blockIdx.x * blockDim.x + threadIdx.x;
  if (gid >= 622592) return;
  float v;
  if (gid < 32768) v = a[gid];
  else if (gid < 98304) v = b[gid - 32768];
  else if (gid < 360448) v = c[gid - 98304];
  else v = d[gid - 360448];
  out[gid] = __float2bfloat16(v);
}

__global__ void zero_ints(int* __restrict__ p, int n) {
  int i = blockIdx.x * blockDim.x + threadIdx.x;
  if (i < n) p[i] = 0;
}

// ---- CSR build ----
__global__ void hist_kernel(const int* __restrict__ ei, int E, int* __restrict__ deg) {
  int e = blockIdx.x * blockDim.x + threadIdx.x;
  if (e < E) atomicAdd(&deg[ei[E + e]], 1);
}

__global__ __launch_bounds__(256) void block_sums(const int* __restrict__ deg,
                                                  int* __restrict__ bsum, int N) {
  int t = threadIdx.x;
  int idx = blockIdx.x * 1024 + t * 4;
  int4 v = {0, 0, 0, 0};
  if (idx + 3 < N) v = *reinterpret_cast<const int4*>(deg + idx);
  else {
    if (idx + 0 < N) v.x = deg[idx + 0];
    if (idx + 1 < N) v.y = deg[idx + 1];
    if (idx + 2 < N) v.z = deg[idx + 2];
    if (idx + 3 < N) v.w = deg[idx + 3];
  }
  int s = v.x + v.y + v.z + v.w;
#pragma unroll
  for (int off = 32; off > 0; off >>= 1) s += __shfl_down(s, off);
  __shared__ int ws[4];
  int lane = t & 63, w = t >> 6;
  if (lane == 0) ws[w] = s;
  __syncthreads();
  if (t == 0) bsum[blockIdx.x] = ws[0] + ws[1] + ws[2] + ws[3];
}

__global__ void scan_bsums(int* __restrict__ bsum, int nb) {
  int t = threadIdx.x;
  int orig = (t < nb) ? bsum[t] : 0;
  int v = orig;
#pragma unroll
  for (int off = 1; off < 64; off <<= 1) {
    int u = __shfl_up(v, off);
    if (t >= off) v += u;
  }
  if (t < nb) bsum[t] = v - orig;  // exclusive
}

__global__ __launch_bounds__(256) void scan_apply(const int* __restrict__ deg,
                                                  const int* __restrict__ bsum_ex,
                                                  int* __restrict__ row_start, int N) {
  int t = threadIdx.x;
  int idx = blockIdx.x * 1024 + t * 4;
  int4 v = {0, 0, 0, 0};
  if (idx + 3 < N) v = *reinterpret_cast<const int4*>(deg + idx);
  else {
    if (idx + 0 < N) v.x = deg[idx + 0];
    if (idx + 1 < N) v.y = deg[idx + 1];
    if (idx + 2 < N) v.z = deg[idx + 2];
    if (idx + 3 < N) v.w = deg[idx + 3];
  }
  int s = v.x + v.y + v.z + v.w;
  int lane = t & 63, w = t >> 6;
  int sc = s;
#pragma unroll
  for (int off = 1; off < 64; off <<= 1) {
    int u = __shfl_up(sc, off);
    if (lane >= off) sc += u;
  }
  __shared__ int woff[4];
  if (lane == 63) woff[w] = sc;
  __syncthreads();
  int boff = bsum_ex[blockIdx.x];
#pragma unroll
  for (int i = 0; i < 4; ++i)
    if (i < w) boff += woff[i];
  int ex = boff + sc - s;
  if (idx + 3 < N) {
    int4 o;
    o.x = ex;
    o.y = ex + v.x;
    o.z = ex + v.x + v.y;
    o.w = ex + v.x + v.y + v.z;
    *reinterpret_cast<int4*>(row_start + idx) = o;
  } else {
    if (idx + 0 < N) row_start[idx + 0] = ex;
    if (idx + 1 < N) row_start[idx + 1] = ex + v.x;
    if (idx + 2 < N) row_start[idx + 2] = ex + v.x + v.y;
    if (idx + 3 < N) row_start[idx + 3] = ex + v.x + v.y + v.z;
  }
}

__global__ void fill_kernel(const int* __restrict__ ei, int E,
                            const int* __restrict__ row_start,
                            int* __restrict__ cursor, int* __restrict__ csr) {
  int e = blockIdx.x * blockDim.x + threadIdx.x;
  if (e >= E) return;
  int d = ei[E + e];
  int p = atomicAdd(&cursor[d], 1);
  csr[row_start[d] + p] = ei[e];
}

// ---- fused aggregation: pre[n] = bf16( (1+eps)*h[n] + sum_{s in in(n)} h[s] ) ----
// half-wave (32 lanes) per node; lane holds 16 B of the row. Neighbor indices
// are preloaded 32-at-a-time (one coalesced load) and broadcast via shfl so
// the row loads have no index-load dependency; 4 rows in flight.
template <int D, bool IN_F32>
__global__ __launch_bounds__(256) void aggregate(const void* __restrict__ hin,
                                                 const int* __restrict__ csr,
                                                 const int* __restrict__ row_start,
                                                 const int* __restrict__ deg,
                                                 const float* __restrict__ eps_all,
                                                 int layer,
                                                 unsigned short* __restrict__ pre,
                                                 int N) {
  const int half = threadIdx.x >> 5;  // 0..7
  const int lane = threadIdx.x & 31;
  const int node = blockIdx.x * 8 + half;
  if (node >= N) return;

  const int start = row_start[node];
  const int cnt = deg[node];

  if (IN_F32) {  // D=128 fp32: lane holds float4
    const float* hf = (const float*)hin;
    f32x4 self = *reinterpret_cast<const f32x4*>(hf + (size_t)node * D + lane * 4);
    f32x4 acc = 0.0f;
    for (int base = 0; base < cnt; base += 32) {
      int m = cnt - base;
      if (m > 32) m = 32;
      int idx = (lane < m) ? csr[start + base + lane] : 0;
      int i = 0;
      for (; i + 4 <= m; i += 4) {
        int s0 = __shfl(idx, i + 0, 32);
        int s1 = __shfl(idx, i + 1, 32);
        int s2 = __shfl(idx, i + 2, 32);
        int s3 = __shfl(idx, i + 3, 32);
        f32x4 v0 = *reinterpret_cast<const f32x4*>(hf + (size_t)s0 * D + lane * 4);
        f32x4 v1 = *reinterpret_cast<const f32x4*>(hf + (size_t)s1 * D + lane * 4);
        f32x4 v2 = *reinterpret_cast<const f32x4*>(hf + (size_t)s2 * D + lane * 4);
        f32x4 v3 = *reinterpret_cast<const f32x4*>(hf + (size_t)s3 * D + lane * 4);
        acc += (v0 + v1) + (v2 + v3);
      }
      for (; i < m; ++i) {
        int s0 = __shfl(idx, i, 32);
        acc += *reinterpret_cast<const f32x4*>(hf + (size_t)s0 * D + lane * 4);
      }
    }
    float epsv = 1.0f + eps_all[layer];
    acc += self * epsv;
    ushort4 o;
    o.x = bfbits(acc[0]);
    o.y = bfbits(acc[1]);
    o.z = bfbits(acc[2]);
    o.w = bfbits(acc[3]);
    *reinterpret_cast<ushort4*>(pre + (size_t)node * D + lane * 4) = o;
  } else {  // D=256 bf16: lane holds ushort8
    const unsigned short* hb = (const unsigned short*)hin;
    u16x8 su = *reinterpret_cast<const u16x8*>(hb + (size_t)node * D + lane * 8);
    float acc[8];
#pragma unroll
    for (int j = 0; j < 8; ++j) acc[j] = 0.0f;
    for (int base = 0; base < cnt; base += 32) {
      int m = cnt - base;
      if (m > 32) m = 32;
      int idx = (lane < m) ? csr[start + base + lane] : 0;
      int i = 0;
      for (; i + 4 <= m; i += 4) {
        int s0 = __shfl(idx, i + 0, 32);
        int s1 = __shfl(idx, i + 1, 32);
        int s2 = __shfl(idx, i + 2, 32);
        int s3 = __shfl(idx, i + 3, 32);
        u16x8 u0 = *reinterpret_cast<const u16x8*>(hb + (size_t)s0 * D + lane * 8);
        u16x8 u1 = *reinterpret_cast<const u16x8*>(hb + (size_t)s1 * D + lane * 8);
        u16x8 u2 = *reinterpret_cast<const u16x8*>(hb + (size_t)s2 * D + lane * 8);
        u16x8 u3 = *reinterpret_cast<const u16x8*>(hb + (size_t)s3 * D + lane * 8);
#pragma unroll
        for (int j = 0; j < 8; ++j)
          acc[j] += (bf2f(u0[j]) + bf2f(u1[j])) + (bf2f(u2[j]) + bf2f(u3[j]));
      }
      for (; i < m; ++i) {
        int s0 = __shfl(idx, i, 32);
        u16x8 u0 = *reinterpret_cast<const u16x8*>(hb + (size_t)s0 * D + lane * 8);
#pragma unroll
        for (int j = 0; j < 8; ++j) acc[j] += bf2f(u0[j]);
      }
    }
    float epsv = 1.0f + eps_all[layer];
    u16x8 o;
#pragma unroll
    for (int j = 0; j < 8; ++j) o[j] = bfbits(acc[j] + epsv * bf2f(su[j]));
    *reinterpret_cast<u16x8*>(pre + (size_t)node * D + lane * 8) = o;
  }
}

// ---- fused 2-layer MLP: out = relu( relu(A@W0.T+b0) @ W1.T + b1 ) ----
// block = 2 waves (128 thr); block covers 32 rows x 256 cols; wave 32x128.
// k-loop double-buffered: prefetch k+32 fragments before MFMAing k.
// mfma_f32_16x16x32_bf16 frag maps: A/B row/col = lane&15, k = (lane>>4)*8 + j;
// C/D: col = lane&15, row = (lane>>4)*4 + reg.
template <int K0, bool OUT_BF16>
__global__ __launch_bounds__(128) void gin_mlp(const __hip_bfloat16* __restrict__ Ap,
                                               const __hip_bfloat16* __restrict__ W0,
                                               const float* __restrict__ b0,
                                               const __hip_bfloat16* __restrict__ W1,
                                               const float* __restrict__ b1,
                                               void* __restrict__ Outp, int Nrows) {
  __shared__ unsigned short mid[32 * MID_STRIDE];  // 16.6 KB

  const int lane = threadIdx.x & 63;
  const int wave = threadIdx.x >> 6;  // 0..1
  const int l15 = lane & 15;
  const int kg = lane >> 4;  // 0..3
  const int row0 = blockIdx.x * 32;
  const int col0 = wave * 128;

  // clamped A-row pointers (garbage rows only feed discarded C rows)
  const __hip_bfloat16* arow[2];
#pragma unroll
  for (int rt = 0; rt < 2; ++rt) {
    int m = row0 + rt * 16 + l15;
    if (m > Nrows - 1) m = Nrows - 1;
    arow[rt] = Ap + (size_t)m * K0 + kg * 8;
  }
  const __hip_bfloat16* w0row[8];
#pragma unroll
  for (int ct = 0; ct < 8; ++ct)
    w0row[ct] = W0 + (size_t)(col0 + ct * 16 + l15) * K0 + kg * 8;

  // ---- GEMM0 (pipelined) ----
  f32x4 acc0[2][8];
#pragma unroll
  for (int rt = 0; rt < 2; ++rt)
#pragma unroll
    for (int ct = 0; ct < 8; ++ct) acc0[rt][ct] = 0.0f;

  constexpr int NK0 = K0 / 32;
  bf16x8 a_cur[2], b_cur[8];
#pragma unroll
  for (int rt = 0; rt < 2; ++rt)
    a_cur[rt] = *reinterpret_cast<const bf16x8*>(arow[rt]);
#pragma unroll
  for (int ct = 0; ct < 8; ++ct)
    b_cur[ct] = *reinterpret_cast<const bf16x8*>(w0row[ct]);

#pragma unroll
  for (int kk = 0; kk < NK0; ++kk) {
    bf16x8 a_nxt[2], b_nxt[8];
    if (kk + 1 < NK0) {
      const int off = (kk + 1) * 32;
#pragma unroll
      for (int rt = 0; rt < 2; ++rt)
        a_nxt[rt] = *reinterpret_cast<const bf16x8*>(arow[rt] + off);
#pragma unroll
      for (int ct = 0; ct < 8; ++ct)
        b_nxt[ct] = *reinterpret_cast<const bf16x8*>(w0row[ct] + off);
    }
#pragma unroll
    for (int rt = 0; rt < 2; ++rt)
#pragma unroll
      for (int ct = 0; ct < 8; ++ct)
        acc0[rt][ct] = __builtin_amdgcn_mfma_f32_16x16x32_bf16(a_cur[rt], b_cur[ct],
                                                               acc0[rt][ct], 0, 0, 0);
    if (kk + 1 < NK0) {
#pragma unroll
      for (int rt = 0; rt < 2; ++rt) a_cur[rt] = a_nxt[rt];
#pragma unroll
      for (int ct = 0; ct < 8; ++ct) b_cur[ct] = b_nxt[ct];
    }
  }

  // epilogue0 -> LDS (bf16, relu)
#pragma unroll
  for (int rt = 0; rt < 2; ++rt) {
#pragma unroll
    for (int ct = 0; ct < 8; ++ct) {
      int col = col0 + ct * 16 + l15;
      float bv = b0[col];
#pragma unroll
      for (int i = 0; i < 4; ++i) {
        int row_l = rt * 16 + kg * 4 + i;
        mid[row_l * MID_STRIDE + col] = bfbits(fmaxf(acc0[rt][ct][i] + bv, 0.0f));
      }
    }
  }
  __syncthreads();

  // ---- GEMM1 (A from LDS, K=256; B pipelined from global) ----
  const unsigned short* w1row_s = (const unsigned short*)W1;
  const unsigned short* w1row[8];
#pragma unroll
  for (int ct = 0; ct < 8; ++ct)
    w1row[ct] = w1row_s + (size_t)(col0 + ct * 16 + l15) * D_H + kg * 8;

  f32x4 acc1[2][8];
#pragma unroll
  for (int rt = 0; rt < 2; ++rt)
#pragma unroll
    for (int ct = 0; ct < 8; ++ct) acc1[rt][ct] = 0.0f;

  constexpr int NK1 = D_H / 32;
  bf16x8 w_cur[8];
#pragma unroll
  for (int ct = 0; ct < 8; ++ct)
    w_cur[ct] = *reinterpret_cast<const bf16x8*>(w1row[ct]);

#pragma unroll
  for (int kk = 0; kk < NK1; ++kk) {
    bf16x8 w_nxt[8];
    if (kk + 1 < NK1) {
      const int off = (kk + 1) * 32;
#pragma unroll
      for (int ct = 0; ct < 8; ++ct)
        w_nxt[ct] = *reinterpret_cast<const bf16x8*>(w1row[ct] + off);
    }
    bf16x8 afr[2];
#pragma unroll
    for (int rt = 0; rt < 2; ++rt) {
      const unsigned short* p = mid + (rt * 16 + l15) * MID_STRIDE + kk * 32 + kg * 8;
      bf16x4 lo = *reinterpret_cast<const bf16x4*>(p);
      bf16x4 hi = *reinterpret_cast<const bf16x4*>(p + 4);
      bf16x8 a;
#pragma unroll
      for (int j = 0; j < 4; ++j) {
        a[j] = lo[j];
        a[j + 4] = hi[j];
      }
      afr[rt] = a;
    }
#pragma unroll
    for (int rt = 0; rt < 2; ++rt)
#pragma unroll
      for (int ct = 0; ct < 8; ++ct)
        acc1[rt][ct] = __builtin_amdgcn_mfma_f32_16x16x32_bf16(afr[rt], w_cur[ct],
                                                               acc1[rt][ct], 0, 0, 0);
    if (kk + 1 < NK1) {
#pragma unroll
      for (int ct = 0; ct < 8; ++ct) w_cur[ct] = w_nxt[ct];
    }
  }

  // epilogue1 -> global (relu)
#pragma unroll
  for (int rt = 0; rt < 2; ++rt) {
#pragma unroll
    for (int ct = 0; ct < 8; ++ct) {
      int col = col0 + ct * 16 + l15;
      float bv = b1[col];
#pragma unroll
      for (int i = 0; i < 4; ++i) {
        int row = row0 + rt * 16 + kg * 4 + i;
        if (row < Nrows) {
          float v = fmaxf(acc1[rt][ct][i] + bv, 0.0f);
          if (OUT_BF16)
            ((__hip_bfloat16*)Outp)[(size_t)row * D_H + col] = __float2bfloat16(v);
          else
            ((float*)Outp)[(size_t)row * D_H + col] = v;
        }
      }
    }
  }
}

extern "C" void kernel_launch(void* const* d_in, const int* in_sizes, int n_in,
                              void* d_out, int out_size, void* d_ws, size_t ws_size,
                              hipStream_t stream) {
  const float* x = (const float*)d_in[0];
  const int* ei = (const int*)d_in[1];  // [2, E]: row0 = src, row1 = dst
  const float* eps_all = (const float*)d_in[2];
  const float* w0_l0 = (const float*)d_in[3];
  const float* b0_l0 = (const float*)d_in[4];
  const float* w1_l0 = (const float*)d_in[5];
  const float* b1_l0 = (const float*)d_in[6];
  const float* w0_rest = (const float*)d_in[7];
  const float* b0_rest = (const float*)d_in[8];
  const float* w1_rest = (const float*)d_in[9];
  const float* b1_rest = (const float*)d_in[10];

  const int N = in_sizes[0] / D_IN;  // 50000
  const int E = in_sizes[1] / 2;     // 800000

  char* ws = (char*)d_ws;
  const size_t node_bf = (size_t)N * D_H * sizeof(unsigned short);  // 25.6 MB
  unsigned short* h = (unsigned short*)ws;  // layer outputs (bf16)
  unsigned short* pre = (unsigned short*)(ws + node_bf);
  char* p = ws + 2 * node_bf;
  __hip_bfloat16* wbf = (__hip_bfloat16*)p;
  p += 622592 * sizeof(__hip_bfloat16);
  int* deg = (int*)p;           // [N]
  int* cursor = deg + N;        // [N]
  int* row_start = cursor + N;  // [N]
  int* bsum = row_start + N;    // [64]
  int* csr = bsum + 64;         // [E]

  __hip_bfloat16* w0_l0_bf = wbf;
  __hip_bfloat16* w1_l0_bf = wbf + 32768;
  __hip_bfloat16* w0_rest_bf = wbf + 98304;
  __hip_bfloat16* w1_rest_bf = w0_rest_bf + 262144;

  conv_weights<<<(622592 + 255) / 256, 256, 0, stream>>>(w0_l0, w1_l0, w0_rest,
                                                         w1_rest, wbf);

  // CSR build
  const int nb = (N + 1023) / 1024;  // 49
  zero_ints<<<(2 * N + 255) / 256, 256, 0, stream>>>(deg, 2 * N);  // deg + cursor
  hist_kernel<<<(E + 255) / 256, 256, 0, stream>>>(ei, E, deg);
  block_sums<<<nb, 256, 0, stream>>>(deg, bsum, N);
  scan_bsums<<<1, 64, 0, stream>>>(bsum, nb);
  scan_apply<<<nb, 256, 0, stream>>>(deg, bsum, row_start, N);
  fill_kernel<<<(E + 255) / 256, 256, 0, stream>>>(ei, E, row_start, cursor, csr);

  const int gemmBlocks = (N + 31) / 32;
  const int aggBlocks = (N + 7) / 8;

  for (int layer = 0; layer < NLAYERS; ++layer) {
    const __hip_bfloat16* w0 =
        (layer == 0) ? w0_l0_bf : w0_rest_bf + (size_t)(layer - 1) * 65536;
    const float* b0 = (layer == 0) ? b0_l0 : b0_rest + (size_t)(layer - 1) * 256;
    const __hip_bfloat16* w1 =
        (layer == 0) ? w1_l0_bf : w1_rest_bf + (size_t)(layer - 1) * 65536;
    const float* b1 = (layer == 0) ? b1_l0 : b1_rest + (size_t)(layer - 1) * 256;

    if (layer == 0) {
      aggregate<D_IN, true><<<aggBlocks, 256, 0, stream>>>(
          x, csr, row_start, deg, eps_all, layer, pre, N);
      gin_mlp<D_IN, true><<<gemmBlocks, 128, 0, stream>>>(
          (const __hip_bfloat16*)pre, w0, b0, w1, b1, h, N);
    } else {
      aggregate<D_H, false><<<aggBlocks, 256, 0, stream>>>(
          h, csr, row_start, deg, eps_all, layer, pre, N);
      if (layer == NLAYERS - 1)
        gin_mlp<D_H, false><<<gemmBlocks, 128, 0, stream>>>(
            (const __hip_bfloat16*)pre, w0, b0, w1, b1, d_out, N);
      else
        gin_mlp<D_H, true><<<gemmBlocks, 128, 0, stream>>>(
            (const __hip_bfloat16*)pre, w0, b0, w1, b1, h, N);
    }
  }
}

// Round 5
// 665.803 us; speedup vs baseline: 1.1300x; 1.1300x over previous
//
#include <hip/hip_runtime.h>
#include <hip/hip_bf16.h>
#include <stdint.h>

#define D_IN 128
#define D_H 256
#define NLAYERS 5

typedef __bf16 bf16x8 __attribute__((ext_vector_type(8)));
typedef __bf16 bf16x4 __attribute__((ext_vector_type(4)));
typedef float f32x4 __attribute__((ext_vector_type(4)));
typedef unsigned short u16x8 __attribute__((ext_vector_type(8)));

// LDS mid-tile row stride in ushorts: 260 u16 = 520 B = 130 dwords (130%32=2
// -> rows spread across banks; measured SQ_LDS_BANK_CONFLICT==0 with this).
#define MID_STRIDE 260

__device__ inline __bf16 f2bf(float f) {
  __hip_bfloat16 h = __float2bfloat16(f);
  __bf16 r;
  __builtin_memcpy(&r, &h, sizeof(r));
  return r;
}

__device__ inline unsigned short bfbits(float f) {
  __hip_bfloat16 h = __float2bfloat16(f);
  unsigned short s;
  __builtin_memcpy(&s, &h, 2);
  return s;
}

__device__ inline float bf2f(unsigned short u) {
  return __uint_as_float((unsigned)u << 16);
}

// convert all 4 weight tensors to bf16 in one launch
__global__ void conv_weights(const float* __restrict__ a, const float* __restrict__ b,
                             const float* __restrict__ c, const float* __restrict__ d,
                             __hip_bfloat16* __restrict__ out) {
  int gid = blockIdx.x * blockDim.x + threadIdx.x;
  if (gid >= 622592) return;
  float v;
  if (gid < 32768) v = a[gid];
  else if (gid < 98304) v = b[gid - 32768];
  else if (gid < 360448) v = c[gid - 98304];
  else v = d[gid - 360448];
  out[gid] = __float2bfloat16(v);
}

__global__ void zero_ints(int* __restrict__ p, int n) {
  int i = blockIdx.x * blockDim.x + threadIdx.x;
  if (i < n) p[i] = 0;
}

// ---- CSR build ----
__global__ void hist_kernel(const int* __restrict__ ei, int E, int* __restrict__ deg) {
  int e = blockIdx.x * blockDim.x + threadIdx.x;
  if (e < E) atomicAdd(&deg[ei[E + e]], 1);
}

__global__ __launch_bounds__(256) void block_sums(const int* __restrict__ deg,
                                                  int* __restrict__ bsum, int N) {
  int t = threadIdx.x;
  int idx = blockIdx.x * 1024 + t * 4;
  int4 v = {0, 0, 0, 0};
  if (idx + 3 < N) v = *reinterpret_cast<const int4*>(deg + idx);
  else {
    if (idx + 0 < N) v.x = deg[idx + 0];
    if (idx + 1 < N) v.y = deg[idx + 1];
    if (idx + 2 < N) v.z = deg[idx + 2];
    if (idx + 3 < N) v.w = deg[idx + 3];
  }
  int s = v.x + v.y + v.z + v.w;
#pragma unroll
  for (int off = 32; off > 0; off >>= 1) s += __shfl_down(s, off);
  __shared__ int ws[4];
  int lane = t & 63, w = t >> 6;
  if (lane == 0) ws[w] = s;
  __syncthreads();
  if (t == 0) bsum[blockIdx.x] = ws[0] + ws[1] + ws[2] + ws[3];
}

__global__ void scan_bsums(int* __restrict__ bsum, int nb) {
  int t = threadIdx.x;
  int orig = (t < nb) ? bsum[t] : 0;
  int v = orig;
#pragma unroll
  for (int off = 1; off < 64; off <<= 1) {
    int u = __shfl_up(v, off);
    if (t >= off) v += u;
  }
  if (t < nb) bsum[t] = v - orig;  // exclusive
}

__global__ __launch_bounds__(256) void scan_apply(const int* __restrict__ deg,
                                                  const int* __restrict__ bsum_ex,
                                                  int* __restrict__ row_start, int N) {
  int t = threadIdx.x;
  int idx = blockIdx.x * 1024 + t * 4;
  int4 v = {0, 0, 0, 0};
  if (idx + 3 < N) v = *reinterpret_cast<const int4*>(deg + idx);
  else {
    if (idx + 0 < N) v.x = deg[idx + 0];
    if (idx + 1 < N) v.y = deg[idx + 1];
    if (idx + 2 < N) v.z = deg[idx + 2];
    if (idx + 3 < N) v.w = deg[idx + 3];
  }
  int s = v.x + v.y + v.z + v.w;
  int lane = t & 63, w = t >> 6;
  int sc = s;
#pragma unroll
  for (int off = 1; off < 64; off <<= 1) {
    int u = __shfl_up(sc, off);
    if (lane >= off) sc += u;
  }
  __shared__ int woff[4];
  if (lane == 63) woff[w] = sc;
  __syncthreads();
  int boff = bsum_ex[blockIdx.x];
#pragma unroll
  for (int i = 0; i < 4; ++i)
    if (i < w) boff += woff[i];
  int ex = boff + sc - s;
  if (idx + 3 < N) {
    int4 o;
    o.x = ex;
    o.y = ex + v.x;
    o.z = ex + v.x + v.y;
    o.w = ex + v.x + v.y + v.z;
    *reinterpret_cast<int4*>(row_start + idx) = o;
  } else {
    if (idx + 0 < N) row_start[idx + 0] = ex;
    if (idx + 1 < N) row_start[idx + 1] = ex + v.x;
    if (idx + 2 < N) row_start[idx + 2] = ex + v.x + v.y;
    if (idx + 3 < N) row_start[idx + 3] = ex + v.x + v.y + v.z;
  }
}

__global__ void fill_kernel(const int* __restrict__ ei, int E,
                            const int* __restrict__ row_start,
                            int* __restrict__ cursor, int* __restrict__ csr) {
  int e = blockIdx.x * blockDim.x + threadIdx.x;
  if (e >= E) return;
  int d = ei[E + e];
  int p = atomicAdd(&cursor[d], 1);
  csr[row_start[d] + p] = ei[e];
}

// ---- fused aggregation: pre[n] = bf16( (1+eps)*h[n] + sum_{s in in(n)} h[s] ) ----
// half-wave (32 lanes) per node; lane holds 16 B of the row. Neighbor indices
// are preloaded 32-at-a-time (one coalesced load) and broadcast via shfl so
// the row loads have no index-load dependency; 4 rows in flight.
template <int D, bool IN_F32>
__global__ __launch_bounds__(256) void aggregate(const void* __restrict__ hin,
                                                 const int* __restrict__ csr,
                                                 const int* __restrict__ row_start,
                                                 const int* __restrict__ deg,
                                                 const float* __restrict__ eps_all,
                                                 int layer,
                                                 unsigned short* __restrict__ pre,
                                                 int N) {
  const int half = threadIdx.x >> 5;  // 0..7
  const int lane = threadIdx.x & 31;
  const int node = blockIdx.x * 8 + half;
  if (node >= N) return;

  const int start = row_start[node];
  const int cnt = deg[node];

  if (IN_F32) {  // D=128 fp32: lane holds float4
    const float* hf = (const float*)hin;
    f32x4 self = *reinterpret_cast<const f32x4*>(hf + (size_t)node * D + lane * 4);
    f32x4 acc = 0.0f;
    for (int base = 0; base < cnt; base += 32) {
      int m = cnt - base;
      if (m > 32) m = 32;
      int idx = (lane < m) ? csr[start + base + lane] : 0;
      int i = 0;
      for (; i + 4 <= m; i += 4) {
        int s0 = __shfl(idx, i + 0, 32);
        int s1 = __shfl(idx, i + 1, 32);
        int s2 = __shfl(idx, i + 2, 32);
        int s3 = __shfl(idx, i + 3, 32);
        f32x4 v0 = *reinterpret_cast<const f32x4*>(hf + (size_t)s0 * D + lane * 4);
        f32x4 v1 = *reinterpret_cast<const f32x4*>(hf + (size_t)s1 * D + lane * 4);
        f32x4 v2 = *reinterpret_cast<const f32x4*>(hf + (size_t)s2 * D + lane * 4);
        f32x4 v3 = *reinterpret_cast<const f32x4*>(hf + (size_t)s3 * D + lane * 4);
        acc += (v0 + v1) + (v2 + v3);
      }
      for (; i < m; ++i) {
        int s0 = __shfl(idx, i, 32);
        acc += *reinterpret_cast<const f32x4*>(hf + (size_t)s0 * D + lane * 4);
      }
    }
    float epsv = 1.0f + eps_all[layer];
    acc += self * epsv;
    ushort4 o;
    o.x = bfbits(acc[0]);
    o.y = bfbits(acc[1]);
    o.z = bfbits(acc[2]);
    o.w = bfbits(acc[3]);
    *reinterpret_cast<ushort4*>(pre + (size_t)node * D + lane * 4) = o;
  } else {  // D=256 bf16: lane holds ushort8
    const unsigned short* hb = (const unsigned short*)hin;
    u16x8 su = *reinterpret_cast<const u16x8*>(hb + (size_t)node * D + lane * 8);
    float acc[8];
#pragma unroll
    for (int j = 0; j < 8; ++j) acc[j] = 0.0f;
    for (int base = 0; base < cnt; base += 32) {
      int m = cnt - base;
      if (m > 32) m = 32;
      int idx = (lane < m) ? csr[start + base + lane] : 0;
      int i = 0;
      for (; i + 4 <= m; i += 4) {
        int s0 = __shfl(idx, i + 0, 32);
        int s1 = __shfl(idx, i + 1, 32);
        int s2 = __shfl(idx, i + 2, 32);
        int s3 = __shfl(idx, i + 3, 32);
        u16x8 u0 = *reinterpret_cast<const u16x8*>(hb + (size_t)s0 * D + lane * 8);
        u16x8 u1 = *reinterpret_cast<const u16x8*>(hb + (size_t)s1 * D + lane * 8);
        u16x8 u2 = *reinterpret_cast<const u16x8*>(hb + (size_t)s2 * D + lane * 8);
        u16x8 u3 = *reinterpret_cast<const u16x8*>(hb + (size_t)s3 * D + lane * 8);
#pragma unroll
        for (int j = 0; j < 8; ++j)
          acc[j] += (bf2f(u0[j]) + bf2f(u1[j])) + (bf2f(u2[j]) + bf2f(u3[j]));
      }
      for (; i < m; ++i) {
        int s0 = __shfl(idx, i, 32);
        u16x8 u0 = *reinterpret_cast<const u16x8*>(hb + (size_t)s0 * D + lane * 8);
#pragma unroll
        for (int j = 0; j < 8; ++j) acc[j] += bf2f(u0[j]);
      }
    }
    float epsv = 1.0f + eps_all[layer];
    u16x8 o;
#pragma unroll
    for (int j = 0; j < 8; ++j) o[j] = bfbits(acc[j] + epsv * bf2f(su[j]));
    *reinterpret_cast<u16x8*>(pre + (size_t)node * D + lane * 8) = o;
  }
}

// ---- fused 2-layer MLP: out = relu( relu(A@W0.T+b0) @ W1.T + b1 ) ----
// block = 4 waves (256 thr); block covers 64 rows (T=2 tiles of 32) x 256 cols;
// wave owns 64 cols for both tiles -> W fragments are loaded once per k-step
// and reused across the 2 row-tiles (MFMA:VMEM = 16:8 per k-step).
// mfma_f32_16x16x32_bf16 frag maps: A/B row/col = lane&15, k = (lane>>4)*8 + j;
// C/D: col = lane&15, row = (lane>>4)*4 + reg.
template <int K0, bool OUT_BF16>
__global__ __launch_bounds__(256) void gin_mlp(const __hip_bfloat16* __restrict__ Ap,
                                               const __hip_bfloat16* __restrict__ W0,
                                               const float* __restrict__ b0,
                                               const __hip_bfloat16* __restrict__ W1,
                                               const float* __restrict__ b1,
                                               void* __restrict__ Outp, int Nrows) {
  __shared__ unsigned short mid[2][32 * MID_STRIDE];  // 33.3 KB

  const int lane = threadIdx.x & 63;
  const int wave = threadIdx.x >> 6;  // 0..3
  const int l15 = lane & 15;
  const int kg = lane >> 4;  // 0..3
  const int row0 = blockIdx.x * 64;
  const int col0 = wave * 64;

  // clamped A-row pointers (garbage rows only feed discarded C rows)
  const __hip_bfloat16* arow[2][2];
#pragma unroll
  for (int t = 0; t < 2; ++t)
#pragma unroll
    for (int rt = 0; rt < 2; ++rt) {
      int m = row0 + t * 32 + rt * 16 + l15;
      if (m > Nrows - 1) m = Nrows - 1;
      arow[t][rt] = Ap + (size_t)m * K0 + kg * 8;
    }
  const __hip_bfloat16* w0row[4];
#pragma unroll
  for (int ct = 0; ct < 4; ++ct)
    w0row[ct] = W0 + (size_t)(col0 + ct * 16 + l15) * K0 + kg * 8;

  // ---- GEMM0 ----
  f32x4 acc0[2][2][4];
#pragma unroll
  for (int t = 0; t < 2; ++t)
#pragma unroll
    for (int rt = 0; rt < 2; ++rt)
#pragma unroll
      for (int ct = 0; ct < 4; ++ct) acc0[t][rt][ct] = 0.0f;

#pragma unroll
  for (int kk = 0; kk < K0 / 32; ++kk) {
    const int off = kk * 32;
    bf16x8 bfr[4];
#pragma unroll
    for (int ct = 0; ct < 4; ++ct)
      bfr[ct] = *reinterpret_cast<const bf16x8*>(w0row[ct] + off);
    bf16x8 afr[2][2];
#pragma unroll
    for (int t = 0; t < 2; ++t)
#pragma unroll
      for (int rt = 0; rt < 2; ++rt)
        afr[t][rt] = *reinterpret_cast<const bf16x8*>(arow[t][rt] + off);
#pragma unroll
    for (int t = 0; t < 2; ++t)
#pragma unroll
      for (int rt = 0; rt < 2; ++rt)
#pragma unroll
        for (int ct = 0; ct < 4; ++ct)
          acc0[t][rt][ct] = __builtin_amdgcn_mfma_f32_16x16x32_bf16(
              afr[t][rt], bfr[ct], acc0[t][rt][ct], 0, 0, 0);
  }

  // epilogue0 -> LDS (bf16, relu)
#pragma unroll
  for (int t = 0; t < 2; ++t)
#pragma unroll
    for (int ct = 0; ct < 4; ++ct) {
      int col = col0 + ct * 16 + l15;
      float bv = b0[col];
#pragma unroll
      for (int rt = 0; rt < 2; ++rt)
#pragma unroll
        for (int i = 0; i < 4; ++i) {
          int row_l = rt * 16 + kg * 4 + i;
          mid[t][row_l * MID_STRIDE + col] =
              bfbits(fmaxf(acc0[t][rt][ct][i] + bv, 0.0f));
        }
    }
  __syncthreads();

  // ---- GEMM1 (A from LDS, K=256) ----
  const unsigned short* w1row[4];
#pragma unroll
  for (int ct = 0; ct < 4; ++ct)
    w1row[ct] = (const unsigned short*)W1 + (size_t)(col0 + ct * 16 + l15) * D_H + kg * 8;

  f32x4 acc1[2][2][4];
#pragma unroll
  for (int t = 0; t < 2; ++t)
#pragma unroll
    for (int rt = 0; rt < 2; ++rt)
#pragma unroll
      for (int ct = 0; ct < 4; ++ct) acc1[t][rt][ct] = 0.0f;

#pragma unroll
  for (int kk = 0; kk < D_H / 32; ++kk) {
    const int off = kk * 32;
    bf16x8 wfr[4];
#pragma unroll
    for (int ct = 0; ct < 4; ++ct)
      wfr[ct] = *reinterpret_cast<const bf16x8*>(w1row[ct] + off);
    bf16x8 afr[2][2];
#pragma unroll
    for (int t = 0; t < 2; ++t)
#pragma unroll
      for (int rt = 0; rt < 2; ++rt) {
        const unsigned short* p = mid[t] + (rt * 16 + l15) * MID_STRIDE + off + kg * 8;
        bf16x4 lo = *reinterpret_cast<const bf16x4*>(p);
        bf16x4 hi = *reinterpret_cast<const bf16x4*>(p + 4);
        bf16x8 a;
#pragma unroll
        for (int j = 0; j < 4; ++j) {
          a[j] = lo[j];
          a[j + 4] = hi[j];
        }
        afr[t][rt] = a;
      }
#pragma unroll
    for (int t = 0; t < 2; ++t)
#pragma unroll
      for (int rt = 0; rt < 2; ++rt)
#pragma unroll
        for (int ct = 0; ct < 4; ++ct)
          acc1[t][rt][ct] = __builtin_amdgcn_mfma_f32_16x16x32_bf16(
              afr[t][rt], wfr[ct], acc1[t][rt][ct], 0, 0, 0);
  }

  // epilogue1 -> global (relu)
#pragma unroll
  for (int t = 0; t < 2; ++t)
#pragma unroll
    for (int ct = 0; ct < 4; ++ct) {
      int col = col0 + ct * 16 + l15;
      float bv = b1[col];
#pragma unroll
      for (int rt = 0; rt < 2; ++rt)
#pragma unroll
        for (int i = 0; i < 4; ++i) {
          int row = row0 + t * 32 + rt * 16 + kg * 4 + i;
          if (row < Nrows) {
            float v = fmaxf(acc1[t][rt][ct][i] + bv, 0.0f);
            if (OUT_BF16)
              ((__hip_bfloat16*)Outp)[(size_t)row * D_H + col] = __float2bfloat16(v);
            else
              ((float*)Outp)[(size_t)row * D_H + col] = v;
          }
        }
    }
}

extern "C" void kernel_launch(void* const* d_in, const int* in_sizes, int n_in,
                              void* d_out, int out_size, void* d_ws, size_t ws_size,
                              hipStream_t stream) {
  const float* x = (const float*)d_in[0];
  const int* ei = (const int*)d_in[1];  // [2, E]: row0 = src, row1 = dst
  const float* eps_all = (const float*)d_in[2];
  const float* w0_l0 = (const float*)d_in[3];
  const float* b0_l0 = (const float*)d_in[4];
  const float* w1_l0 = (const float*)d_in[5];
  const float* b1_l0 = (const float*)d_in[6];
  const float* w0_rest = (const float*)d_in[7];
  const float* b0_rest = (const float*)d_in[8];
  const float* w1_rest = (const float*)d_in[9];
  const float* b1_rest = (const float*)d_in[10];

  const int N = in_sizes[0] / D_IN;  // 50000
  const int E = in_sizes[1] / 2;     // 800000

  char* ws = (char*)d_ws;
  const size_t node_bf = (size_t)N * D_H * sizeof(unsigned short);  // 25.6 MB
  unsigned short* h = (unsigned short*)ws;  // layer outputs (bf16)
  unsigned short* pre = (unsigned short*)(ws + node_bf);
  char* p = ws + 2 * node_bf;
  __hip_bfloat16* wbf = (__hip_bfloat16*)p;
  p += 622592 * sizeof(__hip_bfloat16);
  int* deg = (int*)p;           // [N]
  int* cursor = deg + N;        // [N]
  int* row_start = cursor + N;  // [N]
  int* bsum = row_start + N;    // [64]
  int* csr = bsum + 64;         // [E]

  __hip_bfloat16* w0_l0_bf = wbf;
  __hip_bfloat16* w1_l0_bf = wbf + 32768;
  __hip_bfloat16* w0_rest_bf = wbf + 98304;
  __hip_bfloat16* w1_rest_bf = w0_rest_bf + 262144;

  conv_weights<<<(622592 + 255) / 256, 256, 0, stream>>>(w0_l0, w1_l0, w0_rest,
                                                         w1_rest, wbf);

  // CSR build
  const int nb = (N + 1023) / 1024;  // 49
  zero_ints<<<(2 * N + 255) / 256, 256, 0, stream>>>(deg, 2 * N);  // deg + cursor
  hist_kernel<<<(E + 255) / 256, 256, 0, stream>>>(ei, E, deg);
  block_sums<<<nb, 256, 0, stream>>>(deg, bsum, N);
  scan_bsums<<<1, 64, 0, stream>>>(bsum, nb);
  scan_apply<<<nb, 256, 0, stream>>>(deg, bsum, row_start, N);
  fill_kernel<<<(E + 255) / 256, 256, 0, stream>>>(ei, E, row_start, cursor, csr);

  const int gemmBlocks = (N + 63) / 64;
  const int aggBlocks = (N + 7) / 8;

  for (int layer = 0; layer < NLAYERS; ++layer) {
    const __hip_bfloat16* w0 =
        (layer == 0) ? w0_l0_bf : w0_rest_bf + (size_t)(layer - 1) * 65536;
    const float* b0 = (layer == 0) ? b0_l0 : b0_rest + (size_t)(layer - 1) * 256;
    const __hip_bfloat16* w1 =
        (layer == 0) ? w1_l0_bf : w1_rest_bf + (size_t)(layer - 1) * 65536;
    const float* b1 = (layer == 0) ? b1_l0 : b1_rest + (size_t)(layer - 1) * 256;

    if (layer == 0) {
      aggregate<D_IN, true><<<aggBlocks, 256, 0, stream>>>(
          x, csr, row_start, deg, eps_all, layer, pre, N);
      gin_mlp<D_IN, true><<<gemmBlocks, 256, 0, stream>>>(
          (const __hip_bfloat16*)pre, w0, b0, w1, b1, h, N);
    } else {
      aggregate<D_H, false><<<aggBlocks, 256, 0, stream>>>(
          h, csr, row_start, deg, eps_all, layer, pre, N);
      if (layer == NLAYERS - 1)
        gin_mlp<D_H, false><<<gemmBlocks, 256, 0, stream>>>(
            (const __hip_bfloat16*)pre, w0, b0, w1, b1, d_out, N);
      else
        gin_mlp<D_H, true><<<gemmBlocks, 256, 0, stream>>>(
            (const __hip_bfloat16*)pre, w0, b0, w1, b1, h, N);
    }
  }
}